// Round 1
// baseline (255.860 us; speedup 1.0000x reference)
//
#include <hip/hip_runtime.h>
#include <cstdint>

#define NT 8192
#define DD 1024
#define NE 8
#define BK 32
#define NKIT (DD / BK)
#define TM 64                  // m-tile
#define MAXTILE 136            // sum ceil(c/64) <= 8192/64 + 8

typedef __attribute__((ext_vector_type(8))) _Float16 half8;
typedef __attribute__((ext_vector_type(4))) float f32x4;

__device__ __forceinline__ unsigned short f2h_bits(float f) {
  _Float16 h = (_Float16)f;
  return __builtin_bit_cast(unsigned short, h);
}

// async global->LDS, 16B per lane. LDS dest must be wave-uniform base + lane*16;
// the GLOBAL address is an ordinary per-lane VGPR address (indirection is fine).
#define GLDS16(gp, lp) __builtin_amdgcn_global_load_lds( \
  (__attribute__((address_space(1))) void*)(uintptr_t)(gp), \
  (__attribute__((address_space(3))) void*)(uintptr_t)(lp), 16, 0, 0)

// s_waitcnt imm (gfx9): vmcnt[3:0]|[15:14], expcnt[6:4], lgkmcnt[11:8]; 0xF70|N = vmcnt(N) only
#define WAITCNT_VM6  0xF76
#define WAITCNT_VM3  0xF73
#define WAITCNT_VM0  0xF70

// ---------------- weight cast+transpose: fp32 [e][k][n] -> fp16 [e][n][k] ----------------
__global__ __launch_bounds__(256) void wcast_kernel(
    const float* __restrict__ W1, const float* __restrict__ W2,
    _Float16* __restrict__ W1t, _Float16* __restrict__ W2t) {
  __shared__ float tile[64][65];
  const int z = blockIdx.z;                // 0..15: [0,8)=W1, [8,16)=W2
  const float* W = (z < 8 ? W1 : W2) + (size_t)(z & 7) * (DD * DD);
  _Float16* Wt   = (z < 8 ? W1t : W2t) + (size_t)(z & 7) * (DD * DD);
  const int k0 = blockIdx.x * 64, n0 = blockIdx.y * 64;
  const int tid = threadIdx.x;
#pragma unroll
  for (int it = 0; it < 4; ++it) {
    int idx = it * 256 + tid;              // 0..1023
    int r = idx >> 4;                      // k-row 0..63
    int q = idx & 15;                      // float4 col
    float4 v = *(const float4*)(W + (size_t)(k0 + r) * DD + n0 + q * 4);
    tile[r][q * 4 + 0] = v.x; tile[r][q * 4 + 1] = v.y;
    tile[r][q * 4 + 2] = v.z; tile[r][q * 4 + 3] = v.w;
  }
  __syncthreads();
#pragma unroll
  for (int it = 0; it < 4; ++it) {
    int idx = it * 256 + tid;
    int n = idx >> 4;                      // out row (n) 0..63
    int q = idx & 15;                      // k 4-chunk
    ushort4 o;
    o.x = f2h_bits(tile[q * 4 + 0][n]);
    o.y = f2h_bits(tile[q * 4 + 1][n]);
    o.z = f2h_bits(tile[q * 4 + 2][n]);
    o.w = f2h_bits(tile[q * 4 + 3][n]);
    *(ushort4*)(Wt + (size_t)(n0 + n) * DD + k0 + q * 4) = o;
  }
}

// ---------------- gating: Wg staged to LDS (e-major); also emits xh = fp16(x) ----------------
__global__ __launch_bounds__(256) void gate_kernel(
    const float* __restrict__ x, const float* __restrict__ Wg, const float* __restrict__ bg,
    int* __restrict__ assign, float* __restrict__ wgt, _Float16* __restrict__ xh) {
  __shared__ float WgL[NE * DD];           // 32 KB, e-major: WgL[e*DD + k]
  const int tid = threadIdx.x;
#pragma unroll
  for (int it = 0; it < 8; ++it) {
    int idx = it * 256 + tid;              // float4 index 0..2047
    float4 v = ((const float4*)Wg)[idx];
    int k = idx >> 1;
    int e0 = (idx & 1) * 4;
    WgL[(e0 + 0) * DD + k] = v.x;
    WgL[(e0 + 1) * DD + k] = v.y;
    WgL[(e0 + 2) * DD + k] = v.z;
    WgL[(e0 + 3) * DD + k] = v.w;
  }
  __syncthreads();
  const int lane = tid & 63, w = tid >> 6;
#pragma unroll
  for (int s = 0; s < 2; ++s) {
    const int t = blockIdx.x * 8 + w * 2 + s;
    const float4* xr = (const float4*)(x + (size_t)t * DD);
    float4 xv[4];
#pragma unroll
    for (int c = 0; c < 4; ++c) xv[c] = xr[lane + 64 * c];
    ushort4* xo = (ushort4*)(xh + (size_t)t * DD);
#pragma unroll
    for (int c = 0; c < 4; ++c) {
      union { ushort4 u; _Float16 h[4]; } cv;
      cv.h[0] = (_Float16)xv[c].x; cv.h[1] = (_Float16)xv[c].y;
      cv.h[2] = (_Float16)xv[c].z; cv.h[3] = (_Float16)xv[c].w;
      xo[lane + 64 * c] = cv.u;
    }
    float p[NE];
#pragma unroll
    for (int e = 0; e < NE; ++e) {
      float acc = 0.f;
#pragma unroll
      for (int c = 0; c < 4; ++c) {
        float4 wv = *(const float4*)&WgL[e * DD + 4 * lane + 256 * c];
        acc += xv[c].x * wv.x + xv[c].y * wv.y + xv[c].z * wv.z + xv[c].w * wv.w;
      }
      p[e] = acc;
    }
#pragma unroll
    for (int e = 0; e < NE; ++e) {
      float v = p[e];
      for (int off = 32; off > 0; off >>= 1) v += __shfl_down(v, off, 64);
      p[e] = v;
    }
    if (lane == 0) {
      float l[NE];
#pragma unroll
      for (int e = 0; e < NE; ++e) l[e] = p[e] + bg[e];
      int a = 0; float best = l[0];
#pragma unroll
      for (int e = 1; e < NE; ++e) if (l[e] > best) { best = l[e]; a = e; }
      float sum = 0.f;
#pragma unroll
      for (int e = 0; e < NE; ++e) sum += expf(l[e] - best);
      assign[t] = a;
      wgt[t] = 1.0f / sum;
    }
  }
}

// ---------------- sort: deterministic counting sort + tile plan (64-row tiles) ----------------
__global__ __launch_bounds__(1024) void sort_kernel(
    const int* __restrict__ assign, int* __restrict__ rowtok, int* __restrict__ plan) {
  __shared__ int sc[NE * 1024];            // 32 KB, e-major
  __shared__ int s_pref[NE + 1];
  const int tid = threadIdx.x;
  int a[8];
  int c[NE];
#pragma unroll
  for (int e = 0; e < NE; ++e) c[e] = 0;
#pragma unroll
  for (int j = 0; j < 8; ++j) { a[j] = assign[tid * 8 + j]; ++c[a[j]]; }
#pragma unroll
  for (int e = 0; e < NE; ++e) sc[e * 1024 + tid] = c[e];
  __syncthreads();
  for (int d = 1; d < 1024; d <<= 1) {
    int add[NE];
    if (tid >= d) {
#pragma unroll
      for (int e = 0; e < NE; ++e) add[e] = sc[e * 1024 + tid - d];
    }
    __syncthreads();
    if (tid >= d) {
#pragma unroll
      for (int e = 0; e < NE; ++e) sc[e * 1024 + tid] += add[e];
    }
    __syncthreads();
  }
  int tot[NE], incl[NE];
#pragma unroll
  for (int e = 0; e < NE; ++e) { tot[e] = sc[e * 1024 + 1023]; incl[e] = sc[e * 1024 + tid]; }
  int offs[NE];
  {
    int s = 0;
#pragma unroll
    for (int e = 0; e < NE; ++e) { offs[e] = s; s += tot[e]; }
  }
  int run[NE];
#pragma unroll
  for (int e = 0; e < NE; ++e) run[e] = offs[e] + incl[e] - c[e];
#pragma unroll
  for (int j = 0; j < 8; ++j) { int e = a[j]; rowtok[run[e]++] = tid * 8 + j; }
  // parallel tile-plan build: thread e<8 has everything; prefix over tile counts is cheap
  if (tid == 0) {
    int s = 0;
    for (int e = 0; e < NE; ++e) { s_pref[e] = s; s += (tot[e] + TM - 1) / TM; }
    s_pref[NE] = s;
    plan[0] = s;
  }
  __syncthreads();
  const int nt = s_pref[NE];
  if (tid < nt) {
    int e = 0;
    while (tid >= s_pref[e + 1]) ++e;
    int t = tid - s_pref[e];
    plan[1 + tid] = e;
    plan[1 + MAXTILE + tid] = offs[e] + t * TM;
    plan[1 + 2 * MAXTILE + tid] = offs[e] + tot[e];
  }
}

// ---------------- grouped GEMM: 64x128 tile, BK=32, 4-buffer depth-3 pipeline ----------------
// R0 change: the old dbuf structure waited on loads issued only ONE iteration earlier
// (~150-300cy of cover for ~500-900cy L2/HBM latency) -> every K-iter exposed load latency
// at a block-wide barrier (MfmaUtil 12.7%). Now: 4 LDS buffers (48 KB), prologue stages 3
// tiles, steady-state wait is vmcnt(6) (two tiles stay in flight), ONE barrier per iter.
// Loads get ~3 iterations to land. Tail drains 6->3->0.
// Each of 4 waves: 64m x 32n (acc 4x2). Per thread per iter: 1 A + 2 B GLDS16.
// MODE 0: H[p] = gelu_exact(xh[rowtok[p]] @ W1t^T + b1)  -> fp16
// MODE 1: out[rowtok[p]] = (H[p] @ W2t^T + b2) * wgt      -> fp32 scatter
template <int MODE>
__global__ __launch_bounds__(256) void gemm_kernel(
    const _Float16* __restrict__ A,
    const _Float16* __restrict__ Wt,
    const float* __restrict__ bias,
    const int* __restrict__ plan,
    _Float16* __restrict__ Hout,
    float* __restrict__ Fout,
    const int* __restrict__ rowtok,
    const float* __restrict__ wgt) {
  const int wrk = blockIdx.x;
  const int tile = wrk >> 3;
  if (tile >= plan[0]) return;
  const int e = plan[1 + tile];
  const int m0 = plan[1 + MAXTILE + tile];
  const int seg_end = plan[1 + 2 * MAXTILE + tile];
  const int n0 = (wrk & 7) * 128;

  const int tid = threadIdx.x;
  const int lane = tid & 63;
  const int wn = tid >> 6;             // wave 0..3 -> n strip of 32
  const int quad = lane >> 4;
  const int r15 = lane & 15;

  // LDS: 4 buffers x (A 4KB + B 8KB) = 48 KB -> 3 blocks/CU
  __shared__ alignas(16) char lds[49152];

  // staging addresses. slot -> row = slot>>2, stored chunk sc = slot&3,
  // logical chunk c = sc ^ ((row>>1)&3)  (chunk = 8 halves = 16B)
  const _Float16* We = Wt + (size_t)e * DD * DD;
  const _Float16* gAp;                 // 1 per thread (slot = tid, 64 rows)
  const _Float16* gBp[2];              // 2 per thread (slots tid, tid+256; 128 rows)
  int ldsoA, ldsoB[2];
  {
    int slot = tid;
    int row = slot >> 2;
    int c = (slot & 3) ^ ((row >> 1) & 3);
    int rg = m0 + row; if (rg > NT - 1) rg = NT - 1;
    int arow = (MODE == 0) ? rowtok[rg] : rg;
    gAp = A + (size_t)arow * DD + c * 8;
    ldsoA = slot * 16;
  }
#pragma unroll
  for (int i = 0; i < 2; ++i) {
    int slot = i * 256 + tid;
    int row = slot >> 2;
    int c = (slot & 3) ^ ((row >> 1) & 3);
    gBp[i] = We + (size_t)(n0 + row) * DD + c * 8;
    ldsoB[i] = slot * 16;
  }

  // fragment read offsets (half8 units): row*4 + (quad ^ ((row>>1)&3))
  int aoff[4], boff[2];
#pragma unroll
  for (int i = 0; i < 4; ++i) {
    int m = i * 16 + r15;
    aoff[i] = m * 4 + (quad ^ ((m >> 1) & 3));
  }
#pragma unroll
  for (int i = 0; i < 2; ++i) {
    int n = wn * 32 + i * 16 + r15;
    boff[i] = n * 4 + (quad ^ ((n >> 1) & 3));
  }

  f32x4 acc[4][2];
  f32x4 zero4 = {0.f, 0.f, 0.f, 0.f};
#pragma unroll
  for (int mi = 0; mi < 4; ++mi)
#pragma unroll
    for (int ni = 0; ni < 2; ++ni) acc[mi][ni] = zero4;

#define LDSBUF(B) (lds + (B) * 12288)
#define STAGE(KT, BUF) do {                                          \
    const int ko_ = (KT) * BK;                                       \
    char* lb_ = LDSBUF(BUF);                                         \
    GLDS16(gAp + ko_, lb_ + ldsoA);                                  \
    GLDS16(gBp[0] + ko_, lb_ + 4096 + ldsoB[0]);                     \
    GLDS16(gBp[1] + ko_, lb_ + 4096 + ldsoB[1]);                     \
  } while (0)
#define COMPUTE(BUF) do {                                            \
    const half8* AsV = (const half8*)(LDSBUF(BUF));                  \
    const half8* BsV = (const half8*)(LDSBUF(BUF) + 4096);           \
    half8 a_[4], b_[2];                                              \
    _Pragma("unroll")                                                \
    for (int i = 0; i < 4; ++i) a_[i] = AsV[aoff[i]];                \
    _Pragma("unroll")                                                \
    for (int i = 0; i < 2; ++i) b_[i] = BsV[boff[i]];                \
    _Pragma("unroll")                                                \
    for (int mi = 0; mi < 4; ++mi)                                   \
      _Pragma("unroll")                                              \
      for (int ni = 0; ni < 2; ++ni)                                 \
        acc[mi][ni] = __builtin_amdgcn_mfma_f32_16x16x32_f16(a_[mi], b_[ni], acc[mi][ni], 0, 0, 0); \
  } while (0)

  STAGE(0, 0);                         // prologue: fill 3 buffers (9 loads in flight)
  STAGE(1, 1);
  STAGE(2, 2);

#pragma unroll 1
  for (int kt = 0; kt < NKIT - 3; ++kt) {
    __builtin_amdgcn_s_waitcnt(WAITCNT_VM6);   // own 3 loads of buf kt landed; kt+1,kt+2 in flight
    __builtin_amdgcn_s_barrier();              // all waves: buf kt visible; buf (kt+3)&3 free
    __asm__ volatile("" ::: "memory");
    STAGE(kt + 3, (kt + 3) & 3);               // refill; stays in flight across next 2 barriers
    COMPUTE(kt & 3);
  }
  // tail: drain 6 -> 3 -> 0
  __builtin_amdgcn_s_waitcnt(WAITCNT_VM6);
  __builtin_amdgcn_s_barrier();
  __asm__ volatile("" ::: "memory");
  COMPUTE((NKIT - 3) & 3);
  __builtin_amdgcn_s_waitcnt(WAITCNT_VM3);
  __builtin_amdgcn_s_barrier();
  __asm__ volatile("" ::: "memory");
  COMPUTE((NKIT - 2) & 3);
  __builtin_amdgcn_s_waitcnt(WAITCNT_VM0);
  __builtin_amdgcn_s_barrier();
  __asm__ volatile("" ::: "memory");
  COMPUTE((NKIT - 1) & 3);
#undef COMPUTE
#undef STAGE
#undef LDSBUF

  // epilogue. C/D layout: col = lane&15, row = quad*4 + reg
  const float* bptr = bias + (size_t)e * DD;
#pragma unroll
  for (int mi = 0; mi < 4; ++mi) {
    int rowb = m0 + mi * 16 + quad * 4;
#pragma unroll
    for (int r = 0; r < 4; ++r) {
      int gpos = rowb + r;
      if (gpos < seg_end) {
        if (MODE == 0) {
#pragma unroll
          for (int ni = 0; ni < 2; ++ni) {
            int n = n0 + wn * 32 + ni * 16 + r15;
            float val = acc[mi][ni][r] + bptr[n];
            val = 0.5f * val * (1.0f + erff(val * 0.70710678118654752f));
            Hout[(size_t)gpos * DD + n] = (_Float16)val;
          }
        } else {
          int tok = rowtok[gpos];
          float wv = wgt[tok];
          float* orow = Fout + (size_t)tok * DD;
#pragma unroll
          for (int ni = 0; ni < 2; ++ni) {
            int n = n0 + wn * 32 + ni * 16 + r15;
            orow[n] = (acc[mi][ni][r] + bptr[n]) * wv;
          }
        }
      }
    }
  }
}

extern "C" void kernel_launch(void* const* d_in, const int* in_sizes, int n_in,
                              void* d_out, int out_size, void* d_ws, size_t ws_size,
                              hipStream_t stream) {
  const float* x  = (const float*)d_in[0];
  const float* Wg = (const float*)d_in[1];
  const float* bg = (const float*)d_in[2];
  const float* W1 = (const float*)d_in[3];
  const float* b1 = (const float*)d_in[4];
  const float* W2 = (const float*)d_in[5];
  const float* b2 = (const float*)d_in[6];
  float* out = (float*)d_out;

  char* ws = (char*)d_ws;
  const size_t MB16 = (size_t)1 << 24;
  _Float16* W1t = (_Float16*)(ws + 0 * MB16);
  _Float16* W2t = (_Float16*)(ws + 1 * MB16);
  _Float16* xh  = (_Float16*)(ws + 2 * MB16);
  _Float16* H   = (_Float16*)(ws + 3 * MB16);
  int*   assign = (int*)(ws + 4 * MB16);
  int*   rowtok = assign + NT;
  float* wgt    = (float*)(rowtok + NT);
  int*   plan   = (int*)(wgt + NT);    // [1 + 3*MAXTILE]

  wcast_kernel<<<dim3(16, 16, 16), 256, 0, stream>>>(W1, W2, W1t, W2t);
  gate_kernel<<<NT / 8, 256, 0, stream>>>(x, Wg, bg, assign, wgt, xh);
  sort_kernel<<<1, 1024, 0, stream>>>(assign, rowtok, plan);
  gemm_kernel<0><<<MAXTILE * 8, 256, 0, stream>>>(xh, W1t, b1, plan, H, nullptr, rowtok, nullptr);
  gemm_kernel<1><<<MAXTILE * 8, 256, 0, stream>>>(H, W2t, b2, plan, nullptr, out, rowtok, wgt);
}

// Round 3
// 241.935 us; speedup vs baseline: 1.0576x; 1.0576x over previous
//
#include <hip/hip_runtime.h>
#include <cstdint>

#define NT 8192
#define DD 1024
#define NE 8
#define BK 32
#define NKIT (DD / BK)
#define TM 64                  // m-tile
#define MAXTILE 136            // sum ceil(c/64) <= 8192/64 + 8

typedef __attribute__((ext_vector_type(8))) _Float16 half8;
typedef __attribute__((ext_vector_type(4))) float f32x4;

__device__ __forceinline__ unsigned short f2h_bits(float f) {
  _Float16 h = (_Float16)f;
  return __builtin_bit_cast(unsigned short, h);
}

// async global->LDS, 16B per lane. LDS dest must be wave-uniform base + lane*16;
// the GLOBAL address is an ordinary per-lane VGPR address (indirection is fine).
#define GLDS16(gp, lp) __builtin_amdgcn_global_load_lds( \
  (__attribute__((address_space(1))) void*)(uintptr_t)(gp), \
  (__attribute__((address_space(3))) void*)(uintptr_t)(lp), 16, 0, 0)

// s_waitcnt imm (gfx9): vmcnt[3:0]|[15:14], expcnt[6:4], lgkmcnt[11:8]; 0xF70|N = vmcnt(N) only
#define WAITCNT_VM2  0xF72
#define WAITCNT_VM1  0xF71
#define WAITCNT_VM0  0xF70

// ---------------- weight cast+transpose: fp32 [e][k][n] -> fp16 [e][n][k] ----------------
__global__ __launch_bounds__(256) void wcast_kernel(
    const float* __restrict__ W1, const float* __restrict__ W2,
    _Float16* __restrict__ W1t, _Float16* __restrict__ W2t) {
  __shared__ float tile[64][65];
  const int z = blockIdx.z;                // 0..15: [0,8)=W1, [8,16)=W2
  const float* W = (z < 8 ? W1 : W2) + (size_t)(z & 7) * (DD * DD);
  _Float16* Wt   = (z < 8 ? W1t : W2t) + (size_t)(z & 7) * (DD * DD);
  const int k0 = blockIdx.x * 64, n0 = blockIdx.y * 64;
  const int tid = threadIdx.x;
#pragma unroll
  for (int it = 0; it < 4; ++it) {
    int idx = it * 256 + tid;              // 0..1023
    int r = idx >> 4;                      // k-row 0..63
    int q = idx & 15;                      // float4 col
    float4 v = *(const float4*)(W + (size_t)(k0 + r) * DD + n0 + q * 4);
    tile[r][q * 4 + 0] = v.x; tile[r][q * 4 + 1] = v.y;
    tile[r][q * 4 + 2] = v.z; tile[r][q * 4 + 3] = v.w;
  }
  __syncthreads();
#pragma unroll
  for (int it = 0; it < 4; ++it) {
    int idx = it * 256 + tid;
    int n = idx >> 4;                      // out row (n) 0..63
    int q = idx & 15;                      // k 4-chunk
    ushort4 o;
    o.x = f2h_bits(tile[q * 4 + 0][n]);
    o.y = f2h_bits(tile[q * 4 + 1][n]);
    o.z = f2h_bits(tile[q * 4 + 2][n]);
    o.w = f2h_bits(tile[q * 4 + 3][n]);
    *(ushort4*)(Wt + (size_t)(n0 + n) * DD + k0 + q * 4) = o;
  }
}

// ---------------- gating: Wg staged to LDS (e-major); also emits xh = fp16(x) ----------------
__global__ __launch_bounds__(256) void gate_kernel(
    const float* __restrict__ x, const float* __restrict__ Wg, const float* __restrict__ bg,
    int* __restrict__ assign, float* __restrict__ wgt, _Float16* __restrict__ xh) {
  __shared__ float WgL[NE * DD];           // 32 KB, e-major: WgL[e*DD + k]
  const int tid = threadIdx.x;
#pragma unroll
  for (int it = 0; it < 8; ++it) {
    int idx = it * 256 + tid;              // float4 index 0..2047
    float4 v = ((const float4*)Wg)[idx];
    int k = idx >> 1;
    int e0 = (idx & 1) * 4;
    WgL[(e0 + 0) * DD + k] = v.x;
    WgL[(e0 + 1) * DD + k] = v.y;
    WgL[(e0 + 2) * DD + k] = v.z;
    WgL[(e0 + 3) * DD + k] = v.w;
  }
  __syncthreads();
  const int lane = tid & 63, w = tid >> 6;
#pragma unroll
  for (int s = 0; s < 2; ++s) {
    const int t = blockIdx.x * 8 + w * 2 + s;
    const float4* xr = (const float4*)(x + (size_t)t * DD);
    float4 xv[4];
#pragma unroll
    for (int c = 0; c < 4; ++c) xv[c] = xr[lane + 64 * c];
    ushort4* xo = (ushort4*)(xh + (size_t)t * DD);
#pragma unroll
    for (int c = 0; c < 4; ++c) {
      union { ushort4 u; _Float16 h[4]; } cv;
      cv.h[0] = (_Float16)xv[c].x; cv.h[1] = (_Float16)xv[c].y;
      cv.h[2] = (_Float16)xv[c].z; cv.h[3] = (_Float16)xv[c].w;
      xo[lane + 64 * c] = cv.u;
    }
    float p[NE];
#pragma unroll
    for (int e = 0; e < NE; ++e) {
      float acc = 0.f;
#pragma unroll
      for (int c = 0; c < 4; ++c) {
        float4 wv = *(const float4*)&WgL[e * DD + 4 * lane + 256 * c];
        acc += xv[c].x * wv.x + xv[c].y * wv.y + xv[c].z * wv.z + xv[c].w * wv.w;
      }
      p[e] = acc;
    }
#pragma unroll
    for (int e = 0; e < NE; ++e) {
      float v = p[e];
      for (int off = 32; off > 0; off >>= 1) v += __shfl_down(v, off, 64);
      p[e] = v;
    }
    if (lane == 0) {
      float l[NE];
#pragma unroll
      for (int e = 0; e < NE; ++e) l[e] = p[e] + bg[e];
      int a = 0; float best = l[0];
#pragma unroll
      for (int e = 1; e < NE; ++e) if (l[e] > best) { best = l[e]; a = e; }
      float sum = 0.f;
#pragma unroll
      for (int e = 0; e < NE; ++e) sum += expf(l[e] - best);
      assign[t] = a;
      wgt[t] = 1.0f / sum;
    }
  }
}

// ---------------- sort: deterministic counting sort + tile plan (64-row tiles) ----------------
__global__ __launch_bounds__(1024) void sort_kernel(
    const int* __restrict__ assign, int* __restrict__ rowtok, int* __restrict__ plan) {
  __shared__ int sc[NE * 1024];            // 32 KB, e-major
  __shared__ int s_pref[NE + 1];
  const int tid = threadIdx.x;
  int a[8];
  int c[NE];
#pragma unroll
  for (int e = 0; e < NE; ++e) c[e] = 0;
#pragma unroll
  for (int j = 0; j < 8; ++j) { a[j] = assign[tid * 8 + j]; ++c[a[j]]; }
#pragma unroll
  for (int e = 0; e < NE; ++e) sc[e * 1024 + tid] = c[e];
  __syncthreads();
  for (int d = 1; d < 1024; d <<= 1) {
    int add[NE];
    if (tid >= d) {
#pragma unroll
      for (int e = 0; e < NE; ++e) add[e] = sc[e * 1024 + tid - d];
    }
    __syncthreads();
    if (tid >= d) {
#pragma unroll
      for (int e = 0; e < NE; ++e) sc[e * 1024 + tid] += add[e];
    }
    __syncthreads();
  }
  int tot[NE], incl[NE];
#pragma unroll
  for (int e = 0; e < NE; ++e) { tot[e] = sc[e * 1024 + 1023]; incl[e] = sc[e * 1024 + tid]; }
  int offs[NE];
  {
    int s = 0;
#pragma unroll
    for (int e = 0; e < NE; ++e) { offs[e] = s; s += tot[e]; }
  }
  int run[NE];
#pragma unroll
  for (int e = 0; e < NE; ++e) run[e] = offs[e] + incl[e] - c[e];
#pragma unroll
  for (int j = 0; j < 8; ++j) { int e = a[j]; rowtok[run[e]++] = tid * 8 + j; }
  // parallel tile-plan build
  if (tid == 0) {
    int s = 0;
    for (int e = 0; e < NE; ++e) { s_pref[e] = s; s += (tot[e] + TM - 1) / TM; }
    s_pref[NE] = s;
    plan[0] = s;
  }
  __syncthreads();
  const int nt = s_pref[NE];
  if (tid < nt) {
    int e = 0;
    while (tid >= s_pref[e + 1]) ++e;
    int t = tid - s_pref[e];
    plan[1 + tid] = e;
    plan[1 + MAXTILE + tid] = offs[e] + t * TM;
    plan[1 + 2 * MAXTILE + tid] = offs[e] + tot[e];
  }
}

// ---------------- grouped GEMM: 64x128 tile, 512 threads (8 waves), 3-buffer depth-2 ----------------
// R1 post-mortem: depth-3 pipeline was neutral; occupancy FELL to 22% (1.75 waves/SIMD) and
// MfmaUtil stayed 12% -> the machine is TLP-starved, not schedule-starved. R2: double waves
// per block (8 waves, each a 32x32 sub-tile: 2m x 4n grid), shrink LDS to 3 buffers (36 KB)
// -> 4 blocks/CU resident -> ~32 waves/CU (~8/SIMD). Depth-2 prefetch, one barrier/iter,
// counted vmcnt per wave class (waves 0-3 stage A+B = 2 loads/iter, waves 4-7 stage B = 1).
// R2 bench was an infra container failure; audited for barrier-divergence and waitcnt
// deadlock (none: barrier counts uniform, vmcnt ledger closes 0..31), resubmitting as-is.
// MODE 0: H[p] = gelu_exact(xh[rowtok[p]] @ W1t^T + b1)  -> fp16
// MODE 1: out[rowtok[p]] = (H[p] @ W2t^T + b2) * wgt      -> fp32 scatter
template <int MODE>
__global__ __launch_bounds__(512) void gemm_kernel(
    const _Float16* __restrict__ A,
    const _Float16* __restrict__ Wt,
    const float* __restrict__ bias,
    const int* __restrict__ plan,
    _Float16* __restrict__ Hout,
    float* __restrict__ Fout,
    const int* __restrict__ rowtok,
    const float* __restrict__ wgt) {
  const int wrk = blockIdx.x;
  const int tile = wrk >> 3;
  if (tile >= plan[0]) return;
  const int e = plan[1 + tile];
  const int m0 = plan[1 + MAXTILE + tile];
  const int seg_end = plan[1 + 2 * MAXTILE + tile];
  const int n0 = (wrk & 7) * 128;

  const int tid = threadIdx.x;
  const int lane = tid & 63;
  const int wv = tid >> 6;             // wave 0..7
  const int wm = wv >> 2;              // m half 0..1 (32 rows)
  const int wq = wv & 3;               // n quarter 0..3 (32 cols)
  const int quad = lane >> 4;
  const int r15 = lane & 15;

  // LDS: 3 buffers x (A 4KB + B 8KB) = 36 KB -> 4 blocks/CU
  __shared__ alignas(16) char lds[36864];

  // staging addresses. slot -> row = slot>>2, stored chunk sc = slot&3,
  // logical chunk c = sc ^ ((row>>1)&3)  (chunk = 8 halves = 16B)
  const _Float16* We = Wt + (size_t)e * DD * DD;
  const bool isA = (tid < 256);        // waves 0..3 also stage A
  const _Float16* gBp;                 // all 512 threads: one B slot (128 rows x 4 chunks)
  int ldsoB;
  {
    int slot = tid;                    // 0..511
    int row = slot >> 2;               // 0..127
    int c = (slot & 3) ^ ((row >> 1) & 3);
    gBp = We + (size_t)(n0 + row) * DD + c * 8;
    ldsoB = slot * 16;
  }
  const _Float16* gAp = A;             // valid only for tid<256
  int ldsoA = 0;
  if (isA) {
    int slot = tid;                    // 0..255
    int row = slot >> 2;               // 0..63
    int c = (slot & 3) ^ ((row >> 1) & 3);
    int rg = m0 + row; if (rg > NT - 1) rg = NT - 1;
    int arow = (MODE == 0) ? rowtok[rg] : rg;
    gAp = A + (size_t)arow * DD + c * 8;
    ldsoA = slot * 16;
  }
  const int wvu = __builtin_amdgcn_readfirstlane(wv);  // scalar wave id for waitcnt branch

  // fragment read offsets (half8 units): row*4 + (quad ^ ((row>>1)&3))
  int aoff[2], boff[2];
#pragma unroll
  for (int i = 0; i < 2; ++i) {
    int m = wm * 32 + i * 16 + r15;
    aoff[i] = m * 4 + (quad ^ ((m >> 1) & 3));
  }
#pragma unroll
  for (int i = 0; i < 2; ++i) {
    int n = wq * 32 + i * 16 + r15;
    boff[i] = n * 4 + (quad ^ ((n >> 1) & 3));
  }

  f32x4 acc[2][2];
  f32x4 zero4 = {0.f, 0.f, 0.f, 0.f};
#pragma unroll
  for (int mi = 0; mi < 2; ++mi)
#pragma unroll
    for (int ni = 0; ni < 2; ++ni) acc[mi][ni] = zero4;

#define LDSBUF(B) (lds + (B) * 12288)
#define STAGE(KT, BUF) do {                                          \
    const int ko_ = (KT) * BK;                                       \
    char* lb_ = LDSBUF(BUF);                                         \
    GLDS16(gBp + ko_, lb_ + 4096 + ldsoB);                           \
    if (isA) GLDS16(gAp + ko_, lb_ + ldsoA);                         \
  } while (0)
#define COMPUTE(BUF) do {                                            \
    const half8* AsV = (const half8*)(LDSBUF(BUF));                  \
    const half8* BsV = (const half8*)(LDSBUF(BUF) + 4096);           \
    half8 a_[2], b_[2];                                              \
    _Pragma("unroll")                                                \
    for (int i = 0; i < 2; ++i) a_[i] = AsV[aoff[i]];                \
    _Pragma("unroll")                                                \
    for (int i = 0; i < 2; ++i) b_[i] = BsV[boff[i]];                \
    _Pragma("unroll")                                                \
    for (int mi = 0; mi < 2; ++mi)                                   \
      _Pragma("unroll")                                              \
      for (int ni = 0; ni < 2; ++ni)                                 \
        acc[mi][ni] = __builtin_amdgcn_mfma_f32_16x16x32_f16(a_[mi], b_[ni], acc[mi][ni], 0, 0, 0); \
  } while (0)
// steady-state wait: own loads of buf kt landed, buf kt+1's still in flight
#define WAIT_STEADY() do {                                           \
    if (wvu < 4) __builtin_amdgcn_s_waitcnt(WAITCNT_VM2);            \
    else         __builtin_amdgcn_s_waitcnt(WAITCNT_VM1);            \
  } while (0)

  STAGE(0, 0);                         // prologue: fill 2 buffers
  STAGE(1, 1);

  // stage s -> buf s%3 ; compute kt -> buf kt%3. Loop does 30 computes, unrolled x3.
#pragma unroll 1
  for (int kt = 0; kt < NKIT - 2; kt += 3) {
    WAIT_STEADY();
    __builtin_amdgcn_s_barrier();
    __asm__ volatile("" ::: "memory");
    STAGE(kt + 2, 2);
    COMPUTE(0);
    WAIT_STEADY();
    __builtin_amdgcn_s_barrier();
    __asm__ volatile("" ::: "memory");
    STAGE(kt + 3, 0);
    COMPUTE(1);
    WAIT_STEADY();
    __builtin_amdgcn_s_barrier();
    __asm__ volatile("" ::: "memory");
    STAGE(kt + 4, 1);
    COMPUTE(2);
  }
  // tail: computes NKIT-2 (buf 0), NKIT-1 (buf 1); nothing more staged
  WAIT_STEADY();
  __builtin_amdgcn_s_barrier();
  __asm__ volatile("" ::: "memory");
  COMPUTE(0);
  __builtin_amdgcn_s_waitcnt(WAITCNT_VM0);
  __builtin_amdgcn_s_barrier();
  __asm__ volatile("" ::: "memory");
  COMPUTE(1);
#undef WAIT_STEADY
#undef COMPUTE
#undef STAGE
#undef LDSBUF

  // epilogue. C/D layout: col = lane&15, row = quad*4 + reg
  const float* bptr = bias + (size_t)e * DD;
#pragma unroll
  for (int mi = 0; mi < 2; ++mi) {
    int rowb = m0 + wm * 32 + mi * 16 + quad * 4;
#pragma unroll
    for (int r = 0; r < 4; ++r) {
      int gpos = rowb + r;
      if (gpos < seg_end) {
        if (MODE == 0) {
#pragma unroll
          for (int ni = 0; ni < 2; ++ni) {
            int n = n0 + wq * 32 + ni * 16 + r15;
            float val = acc[mi][ni][r] + bptr[n];
            val = 0.5f * val * (1.0f + erff(val * 0.70710678118654752f));
            Hout[(size_t)gpos * DD + n] = (_Float16)val;
          }
        } else {
          int tok = rowtok[gpos];
          float wgl = wgt[tok];
          float* orow = Fout + (size_t)tok * DD;
#pragma unroll
          for (int ni = 0; ni < 2; ++ni) {
            int n = n0 + wq * 32 + ni * 16 + r15;
            orow[n] = (acc[mi][ni][r] + bptr[n]) * wgl;
          }
        }
      }
    }
  }
}

extern "C" void kernel_launch(void* const* d_in, const int* in_sizes, int n_in,
                              void* d_out, int out_size, void* d_ws, size_t ws_size,
                              hipStream_t stream) {
  const float* x  = (const float*)d_in[0];
  const float* Wg = (const float*)d_in[1];
  const float* bg = (const float*)d_in[2];
  const float* W1 = (const float*)d_in[3];
  const float* b1 = (const float*)d_in[4];
  const float* W2 = (const float*)d_in[5];
  const float* b2 = (const float*)d_in[6];
  float* out = (float*)d_out;

  char* ws = (char*)d_ws;
  const size_t MB16 = (size_t)1 << 24;
  _Float16* W1t = (_Float16*)(ws + 0 * MB16);
  _Float16* W2t = (_Float16*)(ws + 1 * MB16);
  _Float16* xh  = (_Float16*)(ws + 2 * MB16);
  _Float16* H   = (_Float16*)(ws + 3 * MB16);
  int*   assign = (int*)(ws + 4 * MB16);
  int*   rowtok = assign + NT;
  float* wgt    = (float*)(rowtok + NT);
  int*   plan   = (int*)(wgt + NT);    // [1 + 3*MAXTILE]

  wcast_kernel<<<dim3(16, 16, 16), 256, 0, stream>>>(W1, W2, W1t, W2t);
  gate_kernel<<<NT / 8, 256, 0, stream>>>(x, Wg, bg, assign, wgt, xh);
  sort_kernel<<<1, 1024, 0, stream>>>(assign, rowtok, plan);
  gemm_kernel<0><<<MAXTILE * 8, 512, 0, stream>>>(xh, W1t, b1, plan, H, nullptr, rowtok, nullptr);
  gemm_kernel<1><<<MAXTILE * 8, 512, 0, stream>>>(H, W2t, b2, plan, nullptr, out, rowtok, wgt);
}

// Round 4
// 239.457 us; speedup vs baseline: 1.0685x; 1.0103x over previous
//
#include <hip/hip_runtime.h>
#include <cstdint>

#define NT 8192
#define DD 1024
#define NE 8
#define BK 32
#define NKIT (DD / BK)
#define TM 128                 // m-tile
#define MAXTILE 72             // sum ceil(c/128) <= 8192/128 + 8

typedef __attribute__((ext_vector_type(8))) _Float16 half8;
typedef __attribute__((ext_vector_type(4))) float f32x4;

__device__ __forceinline__ unsigned short f2h_bits(float f) {
  _Float16 h = (_Float16)f;
  return __builtin_bit_cast(unsigned short, h);
}

// async global->LDS, 16B per lane. LDS dest must be wave-uniform base + lane*16;
// the GLOBAL address is an ordinary per-lane VGPR address (indirection is fine).
#define GLDS16(gp, lp) __builtin_amdgcn_global_load_lds( \
  (__attribute__((address_space(1))) void*)(uintptr_t)(gp), \
  (__attribute__((address_space(3))) void*)(uintptr_t)(lp), 16, 0, 0)

// s_waitcnt imm (gfx9): vmcnt[3:0]|[15:14], expcnt[6:4], lgkmcnt[11:8]; 0xF70|N = vmcnt(N) only
#define WAITCNT_VM4  0xF74
#define WAITCNT_VM0  0xF70

// ---------------- fused prep: wcast (blocks 0..4095) + gate (blocks 4096..5119) ----------------
// wcast: fp32 [e][k][n] -> fp16 [e][n][k].  gate: logits/softmax/argmax + xh=fp16(x).
// Independent computations; fused into one launch so the LDS-transpose-bound wcast and the
// HBM-read-bound gate overlap on the machine instead of serializing.
__global__ __launch_bounds__(256) void prep_kernel(
    const float* __restrict__ W1, const float* __restrict__ W2,
    _Float16* __restrict__ W1t, _Float16* __restrict__ W2t,
    const float* __restrict__ x, const float* __restrict__ Wg, const float* __restrict__ bg,
    int* __restrict__ assign, float* __restrict__ wgt, _Float16* __restrict__ xh) {
  __shared__ alignas(16) char smem[32768];
  const int bid = blockIdx.x;
  const int tid = threadIdx.x;
  if (bid < 4096) {
    // ---- wcast path ----
    float (*tile)[65] = (float (*)[65])smem;   // 64 x 65 floats = 16.6 KB
    const int z = bid >> 8;                    // 0..15: [0,8)=W1, [8,16)=W2
    const float* W = (z < 8 ? W1 : W2) + (size_t)(z & 7) * (DD * DD);
    _Float16* Wt   = (z < 8 ? W1t : W2t) + (size_t)(z & 7) * (DD * DD);
    const int k0 = (bid & 15) * 64, n0 = ((bid >> 4) & 15) * 64;
#pragma unroll
    for (int it = 0; it < 4; ++it) {
      int idx = it * 256 + tid;                // 0..1023
      int r = idx >> 4;                        // k-row 0..63
      int q = idx & 15;                        // float4 col
      float4 v = *(const float4*)(W + (size_t)(k0 + r) * DD + n0 + q * 4);
      tile[r][q * 4 + 0] = v.x; tile[r][q * 4 + 1] = v.y;
      tile[r][q * 4 + 2] = v.z; tile[r][q * 4 + 3] = v.w;
    }
    __syncthreads();
#pragma unroll
    for (int it = 0; it < 4; ++it) {
      int idx = it * 256 + tid;
      int n = idx >> 4;                        // out row (n) 0..63
      int q = idx & 15;                        // k 4-chunk
      ushort4 o;
      o.x = f2h_bits(tile[q * 4 + 0][n]);
      o.y = f2h_bits(tile[q * 4 + 1][n]);
      o.z = f2h_bits(tile[q * 4 + 2][n]);
      o.w = f2h_bits(tile[q * 4 + 3][n]);
      *(ushort4*)(Wt + (size_t)(n0 + n) * DD + k0 + q * 4) = o;
    }
  } else {
    // ---- gate path ----
    float* WgL = (float*)smem;                 // NE*DD floats = 32 KB, e-major
    const int gb = bid - 4096;                 // 0..1023
#pragma unroll
    for (int it = 0; it < 8; ++it) {
      int idx = it * 256 + tid;                // float4 index 0..2047
      float4 v = ((const float4*)Wg)[idx];
      int k = idx >> 1;
      int e0 = (idx & 1) * 4;
      WgL[(e0 + 0) * DD + k] = v.x;
      WgL[(e0 + 1) * DD + k] = v.y;
      WgL[(e0 + 2) * DD + k] = v.z;
      WgL[(e0 + 3) * DD + k] = v.w;
    }
    __syncthreads();
    const int lane = tid & 63, w = tid >> 6;
#pragma unroll
    for (int s = 0; s < 2; ++s) {
      const int t = gb * 8 + w * 2 + s;
      const float4* xr = (const float4*)(x + (size_t)t * DD);
      float4 xv[4];
#pragma unroll
      for (int c = 0; c < 4; ++c) xv[c] = xr[lane + 64 * c];
      ushort4* xo = (ushort4*)(xh + (size_t)t * DD);
#pragma unroll
      for (int c = 0; c < 4; ++c) {
        union { ushort4 u; _Float16 h[4]; } cv;
        cv.h[0] = (_Float16)xv[c].x; cv.h[1] = (_Float16)xv[c].y;
        cv.h[2] = (_Float16)xv[c].z; cv.h[3] = (_Float16)xv[c].w;
        xo[lane + 64 * c] = cv.u;
      }
      float p[NE];
#pragma unroll
      for (int e = 0; e < NE; ++e) {
        float acc = 0.f;
#pragma unroll
        for (int c = 0; c < 4; ++c) {
          float4 wv = *(const float4*)&WgL[e * DD + 4 * lane + 256 * c];
          acc += xv[c].x * wv.x + xv[c].y * wv.y + xv[c].z * wv.z + xv[c].w * wv.w;
        }
        p[e] = acc;
      }
#pragma unroll
      for (int e = 0; e < NE; ++e) {
        float v = p[e];
        for (int off = 32; off > 0; off >>= 1) v += __shfl_down(v, off, 64);
        p[e] = v;
      }
      if (lane == 0) {
        float l[NE];
#pragma unroll
        for (int e = 0; e < NE; ++e) l[e] = p[e] + bg[e];
        int a = 0; float best = l[0];
#pragma unroll
        for (int e = 1; e < NE; ++e) if (l[e] > best) { best = l[e]; a = e; }
        float sum = 0.f;
#pragma unroll
        for (int e = 0; e < NE; ++e) sum += expf(l[e] - best);
        assign[t] = a;
        wgt[t] = 1.0f / sum;
      }
    }
  }
}

// ---------------- sort: deterministic counting sort + tile plan (128-row tiles) ----------------
__global__ __launch_bounds__(1024) void sort_kernel(
    const int* __restrict__ assign, int* __restrict__ rowtok, int* __restrict__ plan) {
  __shared__ int sc[NE * 1024];            // 32 KB, e-major
  __shared__ int s_pref[NE + 1];
  const int tid = threadIdx.x;
  int a[8];
  int c[NE];
#pragma unroll
  for (int e = 0; e < NE; ++e) c[e] = 0;
#pragma unroll
  for (int j = 0; j < 8; ++j) { a[j] = assign[tid * 8 + j]; ++c[a[j]]; }
#pragma unroll
  for (int e = 0; e < NE; ++e) sc[e * 1024 + tid] = c[e];
  __syncthreads();
  for (int d = 1; d < 1024; d <<= 1) {
    int add[NE];
    if (tid >= d) {
#pragma unroll
      for (int e = 0; e < NE; ++e) add[e] = sc[e * 1024 + tid - d];
    }
    __syncthreads();
    if (tid >= d) {
#pragma unroll
      for (int e = 0; e < NE; ++e) sc[e * 1024 + tid] += add[e];
    }
    __syncthreads();
  }
  int tot[NE], incl[NE];
#pragma unroll
  for (int e = 0; e < NE; ++e) { tot[e] = sc[e * 1024 + 1023]; incl[e] = sc[e * 1024 + tid]; }
  int offs[NE];
  {
    int s = 0;
#pragma unroll
    for (int e = 0; e < NE; ++e) { offs[e] = s; s += tot[e]; }
  }
  int run[NE];
#pragma unroll
  for (int e = 0; e < NE; ++e) run[e] = offs[e] + incl[e] - c[e];
#pragma unroll
  for (int j = 0; j < 8; ++j) { int e = a[j]; rowtok[run[e]++] = tid * 8 + j; }
  // parallel tile-plan build
  if (tid == 0) {
    int s = 0;
    for (int e = 0; e < NE; ++e) { s_pref[e] = s; s += (tot[e] + TM - 1) / TM; }
    s_pref[NE] = s;
    plan[0] = s;
  }
  __syncthreads();
  const int nt = s_pref[NE];
  if (tid < nt) {
    int e = 0;
    while (tid >= s_pref[e + 1]) ++e;
    int t = tid - s_pref[e];
    plan[1 + tid] = e;
    plan[1 + MAXTILE + tid] = offs[e] + t * TM;
    plan[1 + 2 * MAXTILE + tid] = offs[e] + tot[e];
  }
}

// ---------------- grouped GEMM: 128x128 tile, 256 threads (4 waves), 3-buffer depth-2 ----------------
// R3 post-mortem: occupancy 22->55% moved MfmaUtil only 12->14% -> constraint is per-wave
// structure, not TLP. Old shape: 32x32/wave = 4 MFMA per 4 ds_read_b128 per barrier interval
// (20cy MFMA vs ~120cy+ of LDS+sync). R4: m97 geometry -> each wave 64x64 (acc 4x4): 16 MFMA
// per 8 ds_read per K-step (2 MFMA/read, 80cy MFMA/interval). 4 waves in 2x2; LDS 3 bufs x
// (A 8KB + B 8KB) = 48 KB -> 3 blocks/CU = 12 waves/CU (m97's operating point, MfmaUtil 37%).
// Counted-vmcnt depth-2 pipeline, uniform vmcnt(4) (4 GLDS16/thread/stage), 1 barrier/iter.
// MODE 0: H[p] = gelu_exact(xh[rowtok[p]] @ W1t^T + b1)  -> fp16
// MODE 1: out[rowtok[p]] = (H[p] @ W2t^T + b2) * wgt      -> fp32 scatter
template <int MODE>
__global__ __launch_bounds__(256, 3) void gemm_kernel(
    const _Float16* __restrict__ A,
    const _Float16* __restrict__ Wt,
    const float* __restrict__ bias,
    const int* __restrict__ plan,
    _Float16* __restrict__ Hout,
    float* __restrict__ Fout,
    const int* __restrict__ rowtok,
    const float* __restrict__ wgt) {
  const int wrk = blockIdx.x;
  const int tile = wrk >> 3;
  if (tile >= plan[0]) return;
  const int e = plan[1 + tile];
  const int m0 = plan[1 + MAXTILE + tile];
  const int seg_end = plan[1 + 2 * MAXTILE + tile];
  const int n0 = (wrk & 7) * 128;

  const int tid = threadIdx.x;
  const int lane = tid & 63;
  const int wv = tid >> 6;             // wave 0..3
  const int wm = wv >> 1;              // m half 0..1 (64 rows)
  const int wq = wv & 1;               // n half 0..1 (64 cols)
  const int quad = lane >> 4;
  const int r15 = lane & 15;

  // LDS: 3 buffers x (A 8KB + B 8KB) = 48 KB -> 3 blocks/CU
  __shared__ alignas(16) char lds[49152];

  // staging: A-tile 128 rows x 32 halves (8 KB) = 512 slots of 16B over 256 threads
  // (2 slots/thread: tid, tid+256). Same for B. slot -> row = slot>>2, stored chunk
  // sc = slot&3, logical chunk c = sc ^ ((row>>1)&3)  (chunk = 8 halves = 16B).
  const _Float16* We = Wt + (size_t)e * DD * DD;
  const _Float16* gAp[2];
  const _Float16* gBp[2];
  int ldsoA[2], ldsoB[2];
#pragma unroll
  for (int i = 0; i < 2; ++i) {
    int slot = i * 256 + tid;
    int row = slot >> 2;               // 0..127
    int c = (slot & 3) ^ ((row >> 1) & 3);
    int rg = m0 + row; if (rg > NT - 1) rg = NT - 1;
    int arow = (MODE == 0) ? rowtok[rg] : rg;
    gAp[i] = A + (size_t)arow * DD + c * 8;
    ldsoA[i] = slot * 16;
    gBp[i] = We + (size_t)(n0 + row) * DD + c * 8;
    ldsoB[i] = slot * 16;
  }

  // fragment read offsets (half8 units): row*4 + (quad ^ ((row>>1)&3))
  int aoff[4], boff[4];
#pragma unroll
  for (int i = 0; i < 4; ++i) {
    int m = wm * 64 + i * 16 + r15;
    aoff[i] = m * 4 + (quad ^ ((m >> 1) & 3));
    int n = wq * 64 + i * 16 + r15;
    boff[i] = n * 4 + (quad ^ ((n >> 1) & 3));
  }

  f32x4 acc[4][4];
  f32x4 zero4 = {0.f, 0.f, 0.f, 0.f};
#pragma unroll
  for (int mi = 0; mi < 4; ++mi)
#pragma unroll
    for (int ni = 0; ni < 4; ++ni) acc[mi][ni] = zero4;

#define LDSBUF(B) (lds + (B) * 16384)
#define STAGE(KT, BUF) do {                                          \
    const int ko_ = (KT) * BK;                                       \
    char* lb_ = LDSBUF(BUF);                                         \
    GLDS16(gAp[0] + ko_, lb_ + ldsoA[0]);                            \
    GLDS16(gAp[1] + ko_, lb_ + ldsoA[1]);                            \
    GLDS16(gBp[0] + ko_, lb_ + 8192 + ldsoB[0]);                     \
    GLDS16(gBp[1] + ko_, lb_ + 8192 + ldsoB[1]);                     \
  } while (0)
#define COMPUTE(BUF) do {                                            \
    const half8* AsV = (const half8*)(LDSBUF(BUF));                  \
    const half8* BsV = (const half8*)(LDSBUF(BUF) + 8192);           \
    half8 a_[4], b_[4];                                              \
    _Pragma("unroll")                                                \
    for (int i = 0; i < 4; ++i) a_[i] = AsV[aoff[i]];                \
    _Pragma("unroll")                                                \
    for (int i = 0; i < 4; ++i) b_[i] = BsV[boff[i]];                \
    _Pragma("unroll")                                                \
    for (int mi = 0; mi < 4; ++mi)                                   \
      _Pragma("unroll")                                              \
      for (int ni = 0; ni < 4; ++ni)                                 \
        acc[mi][ni] = __builtin_amdgcn_mfma_f32_16x16x32_f16(a_[mi], b_[ni], acc[mi][ni], 0, 0, 0); \
  } while (0)

  STAGE(0, 0);                         // prologue: fill 2 buffers (8 loads in flight)
  STAGE(1, 1);

  // stage s -> buf s%3 ; compute kt -> buf kt%3. Loop does 30 computes, unrolled x3.
#pragma unroll 1
  for (int kt = 0; kt < NKIT - 2; kt += 3) {
    __builtin_amdgcn_s_waitcnt(WAITCNT_VM4);   // own 4 loads of buf kt landed; kt+1 in flight
    __builtin_amdgcn_s_barrier();
    __asm__ volatile("" ::: "memory");
    STAGE(kt + 2, 2);
    COMPUTE(0);
    __builtin_amdgcn_s_waitcnt(WAITCNT_VM4);
    __builtin_amdgcn_s_barrier();
    __asm__ volatile("" ::: "memory");
    STAGE(kt + 3, 0);
    COMPUTE(1);
    __builtin_amdgcn_s_waitcnt(WAITCNT_VM4);
    __builtin_amdgcn_s_barrier();
    __asm__ volatile("" ::: "memory");
    STAGE(kt + 4, 1);
    COMPUTE(2);
  }
  // tail: computes NKIT-2 (buf 0), NKIT-1 (buf 1); nothing more staged
  __builtin_amdgcn_s_waitcnt(WAITCNT_VM4);
  __builtin_amdgcn_s_barrier();
  __asm__ volatile("" ::: "memory");
  COMPUTE(0);
  __builtin_amdgcn_s_waitcnt(WAITCNT_VM0);
  __builtin_amdgcn_s_barrier();
  __asm__ volatile("" ::: "memory");
  COMPUTE(1);
#undef COMPUTE
#undef STAGE
#undef LDSBUF

  // epilogue. C/D layout: col = lane&15, row = quad*4 + reg
  const float* bptr = bias + (size_t)e * DD;
#pragma unroll
  for (int mi = 0; mi < 4; ++mi) {
    int rowb = m0 + wm * 64 + mi * 16 + quad * 4;
#pragma unroll
    for (int r = 0; r < 4; ++r) {
      int gpos = rowb + r;
      if (gpos < seg_end) {
        if (MODE == 0) {
#pragma unroll
          for (int ni = 0; ni < 4; ++ni) {
            int n = n0 + wq * 64 + ni * 16 + r15;
            float val = acc[mi][ni][r] + bptr[n];
            val = 0.5f * val * (1.0f + erff(val * 0.70710678118654752f));
            Hout[(size_t)gpos * DD + n] = (_Float16)val;
          }
        } else {
          int tok = rowtok[gpos];
          float wgl = wgt[tok];
          float* orow = Fout + (size_t)tok * DD;
#pragma unroll
          for (int ni = 0; ni < 4; ++ni) {
            int n = n0 + wq * 64 + ni * 16 + r15;
            orow[n] = (acc[mi][ni][r] + bptr[n]) * wgl;
          }
        }
      }
    }
  }
}

extern "C" void kernel_launch(void* const* d_in, const int* in_sizes, int n_in,
                              void* d_out, int out_size, void* d_ws, size_t ws_size,
                              hipStream_t stream) {
  const float* x  = (const float*)d_in[0];
  const float* Wg = (const float*)d_in[1];
  const float* bg = (const float*)d_in[2];
  const float* W1 = (const float*)d_in[3];
  const float* b1 = (const float*)d_in[4];
  const float* W2 = (const float*)d_in[5];
  const float* b2 = (const float*)d_in[6];
  float* out = (float*)d_out;

  char* ws = (char*)d_ws;
  const size_t MB16 = (size_t)1 << 24;
  _Float16* W1t = (_Float16*)(ws + 0 * MB16);
  _Float16* W2t = (_Float16*)(ws + 1 * MB16);
  _Float16* xh  = (_Float16*)(ws + 2 * MB16);
  _Float16* H   = (_Float16*)(ws + 3 * MB16);
  int*   assign = (int*)(ws + 4 * MB16);
  int*   rowtok = assign + NT;
  float* wgt    = (float*)(rowtok + NT);
  int*   plan   = (int*)(wgt + NT);    // [1 + 3*MAXTILE]

  prep_kernel<<<4096 + NT / 8, 256, 0, stream>>>(W1, W2, W1t, W2t, x, Wg, bg, assign, wgt, xh);
  sort_kernel<<<1, 1024, 0, stream>>>(assign, rowtok, plan);
  gemm_kernel<0><<<MAXTILE * 8, 256, 0, stream>>>(xh, W1t, b1, plan, H, nullptr, rowtok, nullptr);
  gemm_kernel<1><<<MAXTILE * 8, 256, 0, stream>>>(H, W2t, b2, plan, nullptr, out, rowtok, wgt);
}

// Round 5
// 230.409 us; speedup vs baseline: 1.1105x; 1.0393x over previous
//
#include <hip/hip_runtime.h>
#include <cstdint>

#define NT 8192
#define DD 1024
#define NE 8
#define BK 32
#define NKIT (DD / BK)
#define TM 128                 // m-tile
#define MAXTILE 72             // sum ceil(c/128) <= 8192/128 + 8
#define TPX (MAXTILE / 8)      // tiles per XCD = 9

typedef __attribute__((ext_vector_type(8))) _Float16 half8;
typedef __attribute__((ext_vector_type(4))) float f32x4;

__device__ __forceinline__ unsigned short f2h_bits(float f) {
  _Float16 h = (_Float16)f;
  return __builtin_bit_cast(unsigned short, h);
}

// async global->LDS, 16B per lane. LDS dest must be wave-uniform base + lane*16;
// the GLOBAL address is an ordinary per-lane VGPR address (indirection is fine).
#define GLDS16(gp, lp) __builtin_amdgcn_global_load_lds( \
  (__attribute__((address_space(1))) void*)(uintptr_t)(gp), \
  (__attribute__((address_space(3))) void*)(uintptr_t)(lp), 16, 0, 0)

// s_waitcnt imm (gfx9): vmcnt[3:0]|[15:14], expcnt[6:4], lgkmcnt[11:8]; 0xF70|N = vmcnt(N) only
#define WAITCNT_VM4  0xF74
#define WAITCNT_VM0  0xF70

// ---------------- fused prep: wcast (blocks 0..4095) + gate (blocks 4096..5119) ----------------
__global__ __launch_bounds__(256) void prep_kernel(
    const float* __restrict__ W1, const float* __restrict__ W2,
    _Float16* __restrict__ W1t, _Float16* __restrict__ W2t,
    const float* __restrict__ x, const float* __restrict__ Wg, const float* __restrict__ bg,
    int* __restrict__ assign, float* __restrict__ wgt, _Float16* __restrict__ xh) {
  __shared__ alignas(16) char smem[32768];
  const int bid = blockIdx.x;
  const int tid = threadIdx.x;
  if (bid < 4096) {
    // ---- wcast path: fp32 [e][k][n] -> fp16 [e][n][k] ----
    float (*tile)[65] = (float (*)[65])smem;   // 64 x 65 floats = 16.6 KB
    const int z = bid >> 8;                    // 0..15: [0,8)=W1, [8,16)=W2
    const float* W = (z < 8 ? W1 : W2) + (size_t)(z & 7) * (DD * DD);
    _Float16* Wt   = (z < 8 ? W1t : W2t) + (size_t)(z & 7) * (DD * DD);
    const int k0 = (bid & 15) * 64, n0 = ((bid >> 4) & 15) * 64;
#pragma unroll
    for (int it = 0; it < 4; ++it) {
      int idx = it * 256 + tid;                // 0..1023
      int r = idx >> 4;                        // k-row 0..63
      int q = idx & 15;                        // float4 col
      float4 v = *(const float4*)(W + (size_t)(k0 + r) * DD + n0 + q * 4);
      tile[r][q * 4 + 0] = v.x; tile[r][q * 4 + 1] = v.y;
      tile[r][q * 4 + 2] = v.z; tile[r][q * 4 + 3] = v.w;
    }
    __syncthreads();
#pragma unroll
    for (int it = 0; it < 4; ++it) {
      int idx = it * 256 + tid;
      int n = idx >> 4;                        // out row (n) 0..63
      int q = idx & 15;                        // k 4-chunk
      ushort4 o;
      o.x = f2h_bits(tile[q * 4 + 0][n]);
      o.y = f2h_bits(tile[q * 4 + 1][n]);
      o.z = f2h_bits(tile[q * 4 + 2][n]);
      o.w = f2h_bits(tile[q * 4 + 3][n]);
      *(ushort4*)(Wt + (size_t)(n0 + n) * DD + k0 + q * 4) = o;
    }
  } else {
    // ---- gate path ----
    float* WgL = (float*)smem;                 // NE*DD floats = 32 KB, e-major
    const int gb = bid - 4096;                 // 0..1023
#pragma unroll
    for (int it = 0; it < 8; ++it) {
      int idx = it * 256 + tid;                // float4 index 0..2047
      float4 v = ((const float4*)Wg)[idx];
      int k = idx >> 1;
      int e0 = (idx & 1) * 4;
      WgL[(e0 + 0) * DD + k] = v.x;
      WgL[(e0 + 1) * DD + k] = v.y;
      WgL[(e0 + 2) * DD + k] = v.z;
      WgL[(e0 + 3) * DD + k] = v.w;
    }
    __syncthreads();
    const int lane = tid & 63, w = tid >> 6;
#pragma unroll
    for (int s = 0; s < 2; ++s) {
      const int t = gb * 8 + w * 2 + s;
      const float4* xr = (const float4*)(x + (size_t)t * DD);
      float4 xv[4];
#pragma unroll
      for (int c = 0; c < 4; ++c) xv[c] = xr[lane + 64 * c];
      ushort4* xo = (ushort4*)(xh + (size_t)t * DD);
#pragma unroll
      for (int c = 0; c < 4; ++c) {
        union { ushort4 u; _Float16 h[4]; } cv;
        cv.h[0] = (_Float16)xv[c].x; cv.h[1] = (_Float16)xv[c].y;
        cv.h[2] = (_Float16)xv[c].z; cv.h[3] = (_Float16)xv[c].w;
        xo[lane + 64 * c] = cv.u;
      }
      float p[NE];
#pragma unroll
      for (int e = 0; e < NE; ++e) {
        float acc = 0.f;
#pragma unroll
        for (int c = 0; c < 4; ++c) {
          float4 wv = *(const float4*)&WgL[e * DD + 4 * lane + 256 * c];
          acc += xv[c].x * wv.x + xv[c].y * wv.y + xv[c].z * wv.z + xv[c].w * wv.w;
        }
        p[e] = acc;
      }
#pragma unroll
      for (int e = 0; e < NE; ++e) {
        float v = p[e];
        for (int off = 32; off > 0; off >>= 1) v += __shfl_down(v, off, 64);
        p[e] = v;
      }
      if (lane == 0) {
        float l[NE];
#pragma unroll
        for (int e = 0; e < NE; ++e) l[e] = p[e] + bg[e];
        int a = 0; float best = l[0];
#pragma unroll
        for (int e = 1; e < NE; ++e) if (l[e] > best) { best = l[e]; a = e; }
        float sum = 0.f;
#pragma unroll
        for (int e = 0; e < NE; ++e) sum += expf(l[e] - best);
        assign[t] = a;
        wgt[t] = 1.0f / sum;
      }
    }
  }
}

// ---------------- sort: deterministic counting sort + tile plan (128-row tiles) ----------------
__global__ __launch_bounds__(1024) void sort_kernel(
    const int* __restrict__ assign, int* __restrict__ rowtok, int* __restrict__ plan) {
  __shared__ int sc[NE * 1024];            // 32 KB, e-major
  __shared__ int s_pref[NE + 1];
  const int tid = threadIdx.x;
  int a[8];
  int c[NE];
#pragma unroll
  for (int e = 0; e < NE; ++e) c[e] = 0;
#pragma unroll
  for (int j = 0; j < 8; ++j) { a[j] = assign[tid * 8 + j]; ++c[a[j]]; }
#pragma unroll
  for (int e = 0; e < NE; ++e) sc[e * 1024 + tid] = c[e];
  __syncthreads();
  for (int d = 1; d < 1024; d <<= 1) {
    int add[NE];
    if (tid >= d) {
#pragma unroll
      for (int e = 0; e < NE; ++e) add[e] = sc[e * 1024 + tid - d];
    }
    __syncthreads();
    if (tid >= d) {
#pragma unroll
      for (int e = 0; e < NE; ++e) sc[e * 1024 + tid] += add[e];
    }
    __syncthreads();
  }
  int tot[NE], incl[NE];
#pragma unroll
  for (int e = 0; e < NE; ++e) { tot[e] = sc[e * 1024 + 1023]; incl[e] = sc[e * 1024 + tid]; }
  int offs[NE];
  {
    int s = 0;
#pragma unroll
    for (int e = 0; e < NE; ++e) { offs[e] = s; s += tot[e]; }
  }
  int run[NE];
#pragma unroll
  for (int e = 0; e < NE; ++e) run[e] = offs[e] + incl[e] - c[e];
#pragma unroll
  for (int j = 0; j < 8; ++j) { int e = a[j]; rowtok[run[e]++] = tid * 8 + j; }
  // parallel tile-plan build
  if (tid == 0) {
    int s = 0;
    for (int e = 0; e < NE; ++e) { s_pref[e] = s; s += (tot[e] + TM - 1) / TM; }
    s_pref[NE] = s;
    plan[0] = s;
  }
  __syncthreads();
  const int nt = s_pref[NE];
  if (tid < nt) {
    int e = 0;
    while (tid >= s_pref[e + 1]) ++e;
    int t = tid - s_pref[e];
    plan[1 + tid] = e;
    plan[1 + MAXTILE + tid] = offs[e] + t * TM;
    plan[1 + 2 * MAXTILE + tid] = offs[e] + tot[e];
  }
}

// ---------------- grouped GEMM: 128x128 tile, 4 waves (64x64 each), 3-buffer depth-2 ----------------
// R4 post-mortem: every block-schedule variant (R0-R4) lands at 46-52us -> bottleneck is
// OUTSIDE the block schedule. FETCH_SIZE 75MB vs ~34MB ideal: old mapping wrk=tile*8+nb put
// the 8 n-blocks sharing one A-tile on 8 DIFFERENT XCDs (bid%8 round-robin), and same-expert
// tiles (sharing the 2MB B-panel) likewise scattered -> every re-fetch is a ~900cy HBM event
// feeding the vmcnt waits. R5: XCD-aware remap: XCD g owns tiles [9g,9g+9) x all 8 n-blocks,
// so A-tiles (256KB) and the expert B-panel (2MB) stay resident in that XCD's 4MB L2.
// MODE 0: H[p] = gelu_exact(xh[rowtok[p]] @ W1t^T + b1)  -> fp16
// MODE 1: out[rowtok[p]] = (H[p] @ W2t^T + b2) * wgt      -> fp32 scatter
template <int MODE>
__global__ __launch_bounds__(256, 3) void gemm_kernel(
    const _Float16* __restrict__ A,
    const _Float16* __restrict__ Wt,
    const float* __restrict__ bias,
    const int* __restrict__ plan,
    _Float16* __restrict__ Hout,
    float* __restrict__ Fout,
    const int* __restrict__ rowtok,
    const float* __restrict__ wgt) {
  const int wrk = blockIdx.x;
  // XCD-aware bijection: g = XCD (bid%8 round-robin), r = rank within XCD.
  // tile = g*TPX + (r>>3), nb = r&7  ->  8x9x8 = 576 pairs, each exactly once.
  const int g = wrk & 7;
  const int r = wrk >> 3;             // 0..71
  const int tile = g * TPX + (r >> 3);
  const int nb = r & 7;
  if (tile >= plan[0]) return;
  const int e = plan[1 + tile];
  const int m0 = plan[1 + MAXTILE + tile];
  const int seg_end = plan[1 + 2 * MAXTILE + tile];
  const int n0 = nb * 128;

  const int tid = threadIdx.x;
  const int lane = tid & 63;
  const int wv = tid >> 6;             // wave 0..3
  const int wm = wv >> 1;              // m half 0..1 (64 rows)
  const int wq = wv & 1;               // n half 0..1 (64 cols)
  const int quad = lane >> 4;
  const int r15 = lane & 15;

  // LDS: 3 buffers x (A 8KB + B 8KB) = 48 KB -> 3 blocks/CU
  __shared__ alignas(16) char lds[49152];

  // staging: A-tile 128 rows x 32 halves (8 KB) = 512 slots of 16B over 256 threads
  // (2 slots/thread: tid, tid+256). Same for B. slot -> row = slot>>2, stored chunk
  // sc = slot&3, logical chunk c = sc ^ ((row>>1)&3)  (chunk = 8 halves = 16B).
  const _Float16* We = Wt + (size_t)e * DD * DD;
  const _Float16* gAp[2];
  const _Float16* gBp[2];
  int ldsoA[2], ldsoB[2];
#pragma unroll
  for (int i = 0; i < 2; ++i) {
    int slot = i * 256 + tid;
    int row = slot >> 2;               // 0..127
    int c = (slot & 3) ^ ((row >> 1) & 3);
    int rg = m0 + row; if (rg > NT - 1) rg = NT - 1;
    int arow = (MODE == 0) ? rowtok[rg] : rg;
    gAp[i] = A + (size_t)arow * DD + c * 8;
    ldsoA[i] = slot * 16;
    gBp[i] = We + (size_t)(n0 + row) * DD + c * 8;
    ldsoB[i] = slot * 16;
  }

  // fragment read offsets (half8 units): row*4 + (quad ^ ((row>>1)&3))
  int aoff[4], boff[4];
#pragma unroll
  for (int i = 0; i < 4; ++i) {
    int m = wm * 64 + i * 16 + r15;
    aoff[i] = m * 4 + (quad ^ ((m >> 1) & 3));
    int n = wq * 64 + i * 16 + r15;
    boff[i] = n * 4 + (quad ^ ((n >> 1) & 3));
  }

  f32x4 acc[4][4];
  f32x4 zero4 = {0.f, 0.f, 0.f, 0.f};
#pragma unroll
  for (int mi = 0; mi < 4; ++mi)
#pragma unroll
    for (int ni = 0; ni < 4; ++ni) acc[mi][ni] = zero4;

#define LDSBUF(B) (lds + (B) * 16384)
#define STAGE(KT, BUF) do {                                          \
    const int ko_ = (KT) * BK;                                       \
    char* lb_ = LDSBUF(BUF);                                         \
    GLDS16(gAp[0] + ko_, lb_ + ldsoA[0]);                            \
    GLDS16(gAp[1] + ko_, lb_ + ldsoA[1]);                            \
    GLDS16(gBp[0] + ko_, lb_ + 8192 + ldsoB[0]);                     \
    GLDS16(gBp[1] + ko_, lb_ + 8192 + ldsoB[1]);                     \
  } while (0)
#define COMPUTE(BUF) do {                                            \
    const half8* AsV = (const half8*)(LDSBUF(BUF));                  \
    const half8* BsV = (const half8*)(LDSBUF(BUF) + 8192);           \
    half8 a_[4], b_[4];                                              \
    _Pragma("unroll")                                                \
    for (int i = 0; i < 4; ++i) a_[i] = AsV[aoff[i]];                \
    _Pragma("unroll")                                                \
    for (int i = 0; i < 4; ++i) b_[i] = BsV[boff[i]];                \
    _Pragma("unroll")                                                \
    for (int mi = 0; mi < 4; ++mi)                                   \
      _Pragma("unroll")                                              \
      for (int ni = 0; ni < 4; ++ni)                                 \
        acc[mi][ni] = __builtin_amdgcn_mfma_f32_16x16x32_f16(a_[mi], b_[ni], acc[mi][ni], 0, 0, 0); \
  } while (0)

  STAGE(0, 0);                         // prologue: fill 2 buffers (8 loads in flight)
  STAGE(1, 1);

  // stage s -> buf s%3 ; compute kt -> buf kt%3. Loop does 30 computes, unrolled x3.
#pragma unroll 1
  for (int kt = 0; kt < NKIT - 2; kt += 3) {
    __builtin_amdgcn_s_waitcnt(WAITCNT_VM4);   // own 4 loads of buf kt landed; kt+1 in flight
    __builtin_amdgcn_s_barrier();
    __asm__ volatile("" ::: "memory");
    STAGE(kt + 2, 2);
    COMPUTE(0);
    __builtin_amdgcn_s_waitcnt(WAITCNT_VM4);
    __builtin_amdgcn_s_barrier();
    __asm__ volatile("" ::: "memory");
    STAGE(kt + 3, 0);
    COMPUTE(1);
    __builtin_amdgcn_s_waitcnt(WAITCNT_VM4);
    __builtin_amdgcn_s_barrier();
    __asm__ volatile("" ::: "memory");
    STAGE(kt + 4, 1);
    COMPUTE(2);
  }
  // tail: computes NKIT-2 (buf 0), NKIT-1 (buf 1); nothing more staged
  __builtin_amdgcn_s_waitcnt(WAITCNT_VM4);
  __builtin_amdgcn_s_barrier();
  __asm__ volatile("" ::: "memory");
  COMPUTE(0);
  __builtin_amdgcn_s_waitcnt(WAITCNT_VM0);
  __builtin_amdgcn_s_barrier();
  __asm__ volatile("" ::: "memory");
  COMPUTE(1);
#undef COMPUTE
#undef STAGE
#undef LDSBUF

  // epilogue. C/D layout: col = lane&15, row = quad*4 + reg
  const float* bptr = bias + (size_t)e * DD;
#pragma unroll
  for (int mi = 0; mi < 4; ++mi) {
    int rowb = m0 + wm * 64 + mi * 16 + quad * 4;
#pragma unroll
    for (int rr = 0; rr < 4; ++rr) {
      int gpos = rowb + rr;
      if (gpos < seg_end) {
        if (MODE == 0) {
#pragma unroll
          for (int ni = 0; ni < 4; ++ni) {
            int n = n0 + wq * 64 + ni * 16 + r15;
            float val = acc[mi][ni][rr] + bptr[n];
            val = 0.5f * val * (1.0f + erff(val * 0.70710678118654752f));
            Hout[(size_t)gpos * DD + n] = (_Float16)val;
          }
        } else {
          int tok = rowtok[gpos];
          float wgl = wgt[tok];
          float* orow = Fout + (size_t)tok * DD;
#pragma unroll
          for (int ni = 0; ni < 4; ++ni) {
            int n = n0 + wq * 64 + ni * 16 + r15;
            orow[n] = (acc[mi][ni][rr] + bptr[n]) * wgl;
          }
        }
      }
    }
  }
}

extern "C" void kernel_launch(void* const* d_in, const int* in_sizes, int n_in,
                              void* d_out, int out_size, void* d_ws, size_t ws_size,
                              hipStream_t stream) {
  const float* x  = (const float*)d_in[0];
  const float* Wg = (const float*)d_in[1];
  const float* bg = (const float*)d_in[2];
  const float* W1 = (const float*)d_in[3];
  const float* b1 = (const float*)d_in[4];
  const float* W2 = (const float*)d_in[5];
  const float* b2 = (const float*)d_in[6];
  float* out = (float*)d_out;

  char* ws = (char*)d_ws;
  const size_t MB16 = (size_t)1 << 24;
  _Float16* W1t = (_Float16*)(ws + 0 * MB16);
  _Float16* W2t = (_Float16*)(ws + 1 * MB16);
  _Float16* xh  = (_Float16*)(ws + 2 * MB16);
  _Float16* H   = (_Float16*)(ws + 3 * MB16);
  int*   assign = (int*)(ws + 4 * MB16);
  int*   rowtok = assign + NT;
  float* wgt    = (float*)(rowtok + NT);
  int*   plan   = (int*)(wgt + NT);    // [1 + 3*MAXTILE]

  prep_kernel<<<4096 + NT / 8, 256, 0, stream>>>(W1, W2, W1t, W2t, x, Wg, bg, assign, wgt, xh);
  sort_kernel<<<1, 1024, 0, stream>>>(assign, rowtok, plan);
  gemm_kernel<0><<<MAXTILE * 8, 256, 0, stream>>>(xh, W1t, b1, plan, H, nullptr, rowtok, nullptr);
  gemm_kernel<1><<<MAXTILE * 8, 256, 0, stream>>>(H, W2t, b2, plan, nullptr, out, rowtok, wgt);
}